// Round 3
// baseline (2582.712 us; speedup 1.0000x reference)
//
#include <hip/hip_runtime.h>
#include <hip/hip_bf16.h>
#include <stdint.h>

static constexpr int N_NODES = 100000;
static constexpr int N_EDGES = 1600000;

// piecewise multi-term ReLU activation: w1*soft(0.1) - w2*soft(0.5),
// w1 = (2*0.5-0.1)/0.5 = 1.8, w2 = 0.8
__device__ __forceinline__ float custom_act(float x) {
  float s1 = fmaxf(x - 0.1f, 0.f) - fmaxf(-x - 0.1f, 0.f);
  float s2 = fmaxf(x - 0.5f, 0.f) - fmaxf(-x - 0.5f, 0.f);
  return 1.8f * s1 - 0.8f * s2;
}

// ---------------- CSR build (per call; d_ws is re-poisoned every launch) ----------------
__global__ __launch_bounds__(256) void hist_k(const int* __restrict__ Ar, const int* __restrict__ Lr,
                                              int* __restrict__ cntA, int* __restrict__ cntL, int E) {
  int e = blockIdx.x * 256 + threadIdx.x;
  if (e < E) {
    atomicAdd(&cntA[Ar[e]], 1);
    atomicAdd(&cntL[Lr[e]], 1);
  }
}

// single-workgroup exclusive scan (1024 threads, shfl wave scan + LDS), grid.x selects array
__global__ __launch_bounds__(1024) void scan_k(const int* __restrict__ cntA, int* __restrict__ rpA,
                                               const int* __restrict__ cntL, int* __restrict__ rpL, int n) {
  const int* cnt = blockIdx.x ? cntL : cntA;
  int* rp = blockIdx.x ? rpL : rpA;
  __shared__ int wsum[16];
  __shared__ int carry_s;
  int tid = threadIdx.x, lane = tid & 63, wv = tid >> 6;
  if (tid == 0) carry_s = 0;
  __syncthreads();
  for (int base = 0; base < n; base += 1024) {
    int i = base + tid;
    int v = (i < n) ? cnt[i] : 0;
    int s = v;
    #pragma unroll
    for (int off = 1; off < 64; off <<= 1) {
      int t = __shfl_up(s, off, 64);
      if (lane >= off) s += t;
    }
    if (lane == 63) wsum[wv] = s;
    __syncthreads();
    if (wv == 0 && lane < 16) {
      int w = wsum[lane];
      #pragma unroll
      for (int off = 1; off < 16; off <<= 1) {
        int t = __shfl_up(w, off, 64);
        if (lane >= off) w += t;
      }
      wsum[lane] = w;
    }
    __syncthreads();
    int carry = carry_s;
    int woff = wv ? wsum[wv - 1] : 0;
    if (i < n) rp[i] = carry + woff + s - v;   // exclusive
    __syncthreads();
    if (tid == 1023) carry_s = carry + woff + s; // grand total so far
    __syncthreads();
  }
  if (tid == 0) rp[n] = carry_s;
}

__global__ __launch_bounds__(256) void scatter_k(const int* __restrict__ Ai, const float* __restrict__ Av,
                                                 const int* __restrict__ rpA, int* __restrict__ curA,
                                                 int* __restrict__ colA, float* __restrict__ valA,
                                                 const int* __restrict__ Li, const float* __restrict__ Lv,
                                                 const int* __restrict__ rpL, int* __restrict__ curL,
                                                 int* __restrict__ colL, float* __restrict__ valL, int E) {
  int e = blockIdx.x * 256 + threadIdx.x;
  if (e >= E) return;
  {
    int r = Ai[e];
    int p = rpA[r] + atomicAdd(&curA[r], 1);
    colA[p] = Ai[E + e];
    valA[p] = Av[e];
  }
  {
    int r = Li[e];
    int p = rpL[r] + atomicAdd(&curL[r], 1);
    colL[p] = Li[E + e];
    valL[p] = Lv[e];
  }
}

// ---------------- gather SpMM: one wave per row, no atomics ----------------
// mode 0: out = relu(acc + bias)          (GCN layer)
// mode 1: out = custom_act(base - acc)    (embedding update; in-place base==out ok)
template<int VEC>
__global__ __launch_bounds__(256) void spmm_k(const int* __restrict__ rp, const int* __restrict__ col,
                                              const float* __restrict__ val, const float* __restrict__ X,
                                              const float* __restrict__ base, const float* __restrict__ bias,
                                              float* __restrict__ out, int mode, int nrows) {
  int lane = threadIdx.x & 63;
  int row = blockIdx.x * 4 + (threadIdx.x >> 6);
  if (row >= nrows) return;
  const int M = VEC * 64;
  int p0 = rp[row], p1 = rp[row + 1];
  float acc[VEC] = {};
  for (int p = p0; p < p1; ++p) {
    int c = col[p];
    float v = val[p];
    if (VEC == 4) {
      const float4 xv = ((const float4*)(X + (size_t)c * M))[lane];
      acc[0] += v * xv.x; acc[1] += v * xv.y; acc[2] += v * xv.z; acc[3] += v * xv.w;
    } else {
      acc[0] += v * X[(size_t)c * M + lane];
    }
  }
  size_t o = (size_t)row * M + (size_t)lane * VEC;
  if (mode == 0) {
    #pragma unroll
    for (int j = 0; j < VEC; ++j) out[o + j] = fmaxf(acc[j] + bias[lane * VEC + j], 0.f);
  } else {
    #pragma unroll
    for (int j = 0; j < VEC; ++j) out[o + j] = custom_act(base[o + j] - acc[j]);
  }
}

// ---------------- generic fp32 SGEMM, 64x64 tile, BK=16, 4x4 per thread ----------------
// C = epi( A1@B1 [+ A2@B2] + bias ), all fp32. epi: 0 none, 1 tanh
__global__ __launch_bounds__(256) void sgemm_k(const float* __restrict__ A1, int K1,
                                               const float* __restrict__ A2, int K2,
                                               const float* __restrict__ B1, const float* __restrict__ B2,
                                               const float* __restrict__ bias,
                                               float* __restrict__ C, int epi,
                                               int nrows, int M) {
  __shared__ float As[16][64];
  __shared__ float Bs[16][64];
  int tx = threadIdx.x, ty = threadIdx.y;
  int tid = ty * 16 + tx;
  int r0 = blockIdx.x * 64, c0 = blockIdx.y * 64;
  float acc[4][4] = {};
  for (int src = 0; src < 2; ++src) {
    const float* A = src ? A2 : A1;
    if (!A) continue;
    int K = src ? K2 : K1;
    const float* B = src ? B2 : B1;
    for (int k0 = 0; k0 < K; k0 += 16) {
      #pragma unroll
      for (int i = 0; i < 4; ++i) {
        int lin = tid + 256 * i;
        int m = lin >> 4, kk = lin & 15;
        int r = r0 + m;
        float v = 0.f;
        if (r < nrows) v = A[(size_t)r * K + (size_t)(k0 + kk)];
        As[kk][m] = v;
      }
      #pragma unroll
      for (int i = 0; i < 4; ++i) {
        int lin = tid + 256 * i;
        int kk = lin >> 6, n = lin & 63;
        Bs[kk][n] = B[(size_t)(k0 + kk) * M + (c0 + n)];
      }
      __syncthreads();
      #pragma unroll
      for (int kk = 0; kk < 16; ++kk) {
        float4 a4 = *(const float4*)&As[kk][ty * 4];
        float4 b4 = *(const float4*)&Bs[kk][tx * 4];
        float av[4] = {a4.x, a4.y, a4.z, a4.w};
        float bv[4] = {b4.x, b4.y, b4.z, b4.w};
        #pragma unroll
        for (int i = 0; i < 4; ++i)
          #pragma unroll
          for (int j = 0; j < 4; ++j) acc[i][j] += av[i] * bv[j];
      }
      __syncthreads();
    }
  }
  float bv[4] = {0.f, 0.f, 0.f, 0.f};
  if (bias) {
    #pragma unroll
    for (int j = 0; j < 4; ++j) bv[j] = bias[c0 + tx * 4 + j];
  }
  #pragma unroll
  for (int i = 0; i < 4; ++i) {
    int r = r0 + ty * 4 + i;
    if (r >= nrows) continue;
    #pragma unroll
    for (int j = 0; j < 4; ++j) {
      float v = acc[i][j] + bv[j];
      if (epi == 1) v = tanhf(v);
      C[(size_t)r * M + (size_t)(c0 + tx * 4 + j)] = v;
    }
  }
}

extern "C" void kernel_launch(void* const* d_in, const int* in_sizes, int n_in,
                              void* d_out, int out_size, void* d_ws, size_t ws_size,
                              hipStream_t stream) {
  const float* x  = (const float*)d_in[0];
  const int*   Ai = (const int*)d_in[1];
  const float* Av = (const float*)d_in[2];
  const int*   Li = (const int*)d_in[3];
  const float* Lv = (const float*)d_in[4];
  const float* gcn_w0 = (const float*)d_in[5];
  const float* gcn_b0 = (const float*)d_in[6];
  const float* pai1_0 = (const float*)d_in[7];
  const float* pai2_0 = (const float*)d_in[8];
  const float* w1_w0  = (const float*)d_in[9];
  const float* w1_b0  = (const float*)d_in[10];
  const float* w2_w0  = (const float*)d_in[11];
  const float* w2_b0  = (const float*)d_in[12];
  const float* gcn_w1 = (const float*)d_in[13];
  const float* gcn_b1 = (const float*)d_in[14];
  const float* pai1_1 = (const float*)d_in[15];
  const float* pai2_1 = (const float*)d_in[16];
  const float* w1_w1  = (const float*)d_in[17];
  const float* w1_b1  = (const float*)d_in[18];
  const float* w2_w1  = (const float*)d_in[19];
  const float* w2_b1  = (const float*)d_in[20];
  float* out = (float*)d_out;   // reference output dtype is float32

  const int N = N_NODES, E = N_EDGES;
  // workspace layout (~233 MB total)
  float* bufA = (float*)d_ws;                       // N*256 f32
  float* bufB = bufA + (size_t)N * 256;             // N*256 f32
  int*   colA = (int*)(bufB + (size_t)N * 256);     // E
  float* valA = (float*)(colA + E);                 // E
  int*   colL = (int*)(valA + E);                   // E
  float* valL = (float*)(colL + E);                 // E
  int*   rpA  = (int*)(valL + E);                   // N+1
  int*   rpL  = rpA + (N + 1);                      // N+1
  int*   cnt  = rpL + (N + 1);                      // 4*N (cntA,cntL,curA,curL)
  int* cntA = cnt, *cntL = cnt + N, *curA = cnt + 2 * N, *curL = cnt + 3 * N;

  hipMemsetAsync(cnt, 0, sizeof(int) * 4 * (size_t)N, stream);
  hist_k<<<(E + 255) / 256, 256, 0, stream>>>(Ai, Li, cntA, cntL, E);
  scan_k<<<2, 1024, 0, stream>>>(cntA, rpA, cntL, rpL, N);
  scatter_k<<<(E + 255) / 256, 256, 0, stream>>>(Ai, Av, rpA, curA, colA, valA,
                                                 Li, Lv, rpL, curL, colL, valL, E);

  dim3 b16(16, 16);
  dim3 g256((N + 63) / 64, 4), g64((N + 63) / 64, 1);
  const size_t Nd = (size_t)N * 64;
  const int spmm_grid = (N + 3) / 4;

  // ---- layer 0 ----
  // T0 = x @ gcn_w0                                   -> bufA (f32 N x 256)
  sgemm_k<<<g256, b16, 0, stream>>>(x, 256, nullptr, 0, gcn_w0, nullptr, nullptr, bufA, 0, N, 256);
  // Ztp0 = relu(A @ T0 + gcn_b0)                      -> bufB
  spmm_k<4><<<spmm_grid, 256, 0, stream>>>(rpA, colA, valA, bufA, nullptr, gcn_b0, bufB, 0, N);
  // out0 = tanh(Ztp0 @ w1_w0 + w1_b0)                 -> d_out[0:Nd]
  sgemm_k<<<g64, b16, 0, stream>>>(bufB, 256, nullptr, 0, w1_w0, nullptr, w1_b0, out, 1, N, 64);
  // Zb = Ztp0 @ pai1_0 + x @ pai2_0                   -> bufA
  sgemm_k<<<g256, b16, 0, stream>>>(bufB, 256, x, 256, pai1_0, pai2_0, nullptr, bufA, 0, N, 256);
  // Zemb0 = act(Zb - L @ Ztp0)                        -> bufA (in place)
  spmm_k<4><<<spmm_grid, 256, 0, stream>>>(rpL, colL, valL, bufB, bufA, nullptr, bufA, 1, N);
  // out2 = tanh(Zemb0 @ w2_w0 + w2_b0)                -> d_out[2Nd:3Nd]
  sgemm_k<<<g64, b16, 0, stream>>>(bufA, 256, nullptr, 0, w2_w0, nullptr, w2_b0, out + 2 * Nd, 1, N, 64);

  // ---- layer 1 ----  (bufB free after the L-SpMM above)
  float* T1   = bufB;            // N x 64
  float* Ztp1 = bufB + Nd;       // N x 64
  float* Z1b  = bufB + 2 * Nd;   // N x 64
  // T1 = Zemb0 @ gcn_w1
  sgemm_k<<<g64, b16, 0, stream>>>(bufA, 256, nullptr, 0, gcn_w1, nullptr, nullptr, T1, 0, N, 64);
  // Ztp1 = relu(A @ T1 + gcn_b1)
  spmm_k<1><<<spmm_grid, 256, 0, stream>>>(rpA, colA, valA, T1, nullptr, gcn_b1, Ztp1, 0, N);
  // out1 = tanh(Ztp1 @ w1_w1 + w1_b1)                 -> d_out[Nd:2Nd]
  sgemm_k<<<g64, b16, 0, stream>>>(Ztp1, 64, nullptr, 0, w1_w1, nullptr, w1_b1, out + Nd, 1, N, 64);
  // Z1b = Ztp1 @ pai1_1 + x @ pai2_1
  sgemm_k<<<g64, b16, 0, stream>>>(Ztp1, 64, x, 256, pai1_1, pai2_1, nullptr, Z1b, 0, N, 64);
  // Zemb1 = act(Z1b - L @ Ztp1)  (in place)
  spmm_k<1><<<spmm_grid, 256, 0, stream>>>(rpL, colL, valL, Ztp1, Z1b, nullptr, Z1b, 1, N);
  // out3 = tanh(Zemb1 @ w2_w1 + w2_b1)                -> d_out[3Nd:4Nd]
  sgemm_k<<<g64, b16, 0, stream>>>(Z1b, 64, nullptr, 0, w2_w1, nullptr, w2_b1, out + 3 * Nd, 1, N, 64);
}

// Round 4
// 1589.892 us; speedup vs baseline: 1.6245x; 1.6245x over previous
//
#include <hip/hip_runtime.h>
#include <hip/hip_bf16.h>
#include <stdint.h>

static constexpr int N_NODES = 100000;
static constexpr int N_EDGES = 1600000;

typedef _Float16 f16;
using f16x8 = __attribute__((ext_vector_type(8))) _Float16;
using f16x4v = __attribute__((ext_vector_type(4))) _Float16;
using f32x4 = __attribute__((ext_vector_type(4))) float;

// piecewise multi-term ReLU activation: 1.8*soft(0.1) - 0.8*soft(0.5)
__device__ __forceinline__ float custom_act(float x) {
  float s1 = fmaxf(x - 0.1f, 0.f) - fmaxf(-x - 0.1f, 0.f);
  float s2 = fmaxf(x - 0.5f, 0.f) - fmaxf(-x - 0.5f, 0.f);
  return 1.8f * s1 - 0.8f * s2;
}

// ---------------- conversions ----------------
__global__ __launch_bounds__(256) void xconv_k(const float* __restrict__ src, f16* __restrict__ dst, int n4) {
  int i = blockIdx.x * 256 + threadIdx.x;
  if (i < n4) {
    float4 v = ((const float4*)src)[i];
    f16x4v h = {(f16)v.x, (f16)v.y, (f16)v.z, (f16)v.w};
    ((f16x4v*)dst)[i] = h;
  }
}
// fp32 [K][N] -> f16 [N][K]
__global__ __launch_bounds__(256) void wconv_k(const float* __restrict__ src, f16* __restrict__ dst, int K, int N) {
  int i = blockIdx.x * 256 + threadIdx.x;
  if (i < K * N) { int k = i / N, n = i - k * N; dst[n * K + k] = (f16)src[i]; }
}

// ---------------- CSR build ----------------
__global__ __launch_bounds__(256) void hist_k(const int* __restrict__ Ar, const int* __restrict__ Lr,
                                              int* __restrict__ cntA, int* __restrict__ cntL, int E) {
  int e = blockIdx.x * 256 + threadIdx.x;
  if (e < E) {
    atomicAdd(&cntA[Ar[e]], 1);
    atomicAdd(&cntL[Lr[e]], 1);
  }
}

__global__ __launch_bounds__(1024) void scan_k(const int* __restrict__ cntA, int* __restrict__ rpA,
                                               const int* __restrict__ cntL, int* __restrict__ rpL, int n) {
  const int* cnt = blockIdx.x ? cntL : cntA;
  int* rp = blockIdx.x ? rpL : rpA;
  __shared__ int wsum[16];
  __shared__ int carry_s;
  int tid = threadIdx.x, lane = tid & 63, wv = tid >> 6;
  if (tid == 0) carry_s = 0;
  __syncthreads();
  for (int base = 0; base < n; base += 1024) {
    int i = base + tid;
    int v = (i < n) ? cnt[i] : 0;
    int s = v;
    #pragma unroll
    for (int off = 1; off < 64; off <<= 1) {
      int t = __shfl_up(s, off, 64);
      if (lane >= off) s += t;
    }
    if (lane == 63) wsum[wv] = s;
    __syncthreads();
    if (wv == 0 && lane < 16) {
      int w = wsum[lane];
      #pragma unroll
      for (int off = 1; off < 16; off <<= 1) {
        int t = __shfl_up(w, off, 64);
        if (lane >= off) w += t;
      }
      wsum[lane] = w;
    }
    __syncthreads();
    int carry = carry_s;
    int woff = wv ? wsum[wv - 1] : 0;
    if (i < n) rp[i] = carry + woff + s - v;
    __syncthreads();
    if (tid == 1023) carry_s = carry + woff + s;
    __syncthreads();
  }
  if (tid == 0) rp[n] = carry_s;
}

__global__ __launch_bounds__(256) void scatter_k(const int* __restrict__ Ai, const float* __restrict__ Av,
                                                 const int* __restrict__ rpA, int* __restrict__ curA,
                                                 int* __restrict__ colA, float* __restrict__ valA,
                                                 const int* __restrict__ Li, const float* __restrict__ Lv,
                                                 const int* __restrict__ rpL, int* __restrict__ curL,
                                                 int* __restrict__ colL, float* __restrict__ valL, int E) {
  int e = blockIdx.x * 256 + threadIdx.x;
  if (e >= E) return;
  {
    int r = Ai[e];
    int p = rpA[r] + atomicAdd(&curA[r], 1);
    colA[p] = Ai[E + e];
    valA[p] = Av[e];
  }
  {
    int r = Li[e];
    int p = rpL[r] + atomicAdd(&curL[r], 1);
    colL[p] = Li[E + e];
    valL[p] = Lv[e];
  }
}

// ---------------- gather SpMM over f16 features, fp32 accumulate ----------------
// mode 0: out = relu(acc + bias);  mode 1: out = custom_act(base - acc) (in-place ok)
template<int VEC>
__global__ __launch_bounds__(256) void spmm_k(const int* __restrict__ rp, const int* __restrict__ col,
                                              const float* __restrict__ val, const f16* __restrict__ X,
                                              const f16* __restrict__ base, const float* __restrict__ bias,
                                              f16* __restrict__ out, int mode, int nrows) {
  int lane = threadIdx.x & 63;
  int row = blockIdx.x * 4 + (threadIdx.x >> 6);
  if (row >= nrows) return;
  const int M = VEC * 64;
  int p0 = rp[row], p1 = rp[row + 1];
  float acc[VEC] = {};
  for (int p = p0; p < p1; ++p) {
    int c = col[p];
    float v = val[p];
    if (VEC == 4) {
      f16x4v xv = *(const f16x4v*)(X + (size_t)c * M + lane * 4);
      acc[0] += v * (float)xv[0]; acc[1] += v * (float)xv[1];
      acc[2] += v * (float)xv[2]; acc[3] += v * (float)xv[3];
    } else {
      acc[0] += v * (float)X[(size_t)c * M + lane];
    }
  }
  size_t o = (size_t)row * M + (size_t)lane * VEC;
  if (VEC == 4) {
    f16x4v r;
    if (mode == 0) {
      #pragma unroll
      for (int j = 0; j < 4; ++j) r[j] = (f16)fmaxf(acc[j] + bias[lane * 4 + j], 0.f);
    } else {
      f16x4v bv = *(const f16x4v*)(base + o);
      #pragma unroll
      for (int j = 0; j < 4; ++j) r[j] = (f16)custom_act((float)bv[j] - acc[j]);
    }
    *(f16x4v*)(out + o) = r;
  } else {
    if (mode == 0) out[o] = (f16)fmaxf(acc[0] + bias[lane], 0.f);
    else out[o] = (f16)custom_act((float)base[o] - acc[0]);
  }
}

// ---------------- f16 MFMA GEMM: C = epi(A1@B1 [+ A2@B2] + bias) ----------------
// A row-major MxK f16; Bt pre-transposed f16 [N][K]; C fp32 or f16.
// tile 128 x BN, BK=32, 4 waves x 32 rows, mfma_f32_16x16x32_f16.
template<int BN>
__global__ __launch_bounds__(256) void gemm_k(const f16* __restrict__ A1, int K1,
                                              const f16* __restrict__ A2, int K2,
                                              const f16* __restrict__ B1t, const f16* __restrict__ B2t,
                                              const float* __restrict__ bias,
                                              void* __restrict__ C, int cf16, int epi,
                                              int nrows, int ldc) {
  constexpr int LD = 40;  // 32 + 8 pad, keeps 16B alignment of quad*8 reads
  __shared__ f16 As[128 * LD];
  __shared__ f16 Bs[BN * LD];
  int tid = threadIdx.x;
  int lane = tid & 63, wv = tid >> 6;
  int m16 = lane & 15, quad = lane >> 4;
  int r0 = blockIdx.x * 128, c0 = blockIdx.y * BN;
  int wr0 = wv * 32;
  f32x4 acc[2][BN / 16] = {};
  for (int src = 0; src < 2; ++src) {
    const f16* A = src ? A2 : A1;
    if (!A) continue;
    int K = src ? K2 : K1;
    const f16* Bt = src ? B2t : B1t;
    for (int k0 = 0; k0 < K; k0 += 32) {
      // stage A tile: 128x32 f16 (coalesced 8B per lane)
      #pragma unroll
      for (int i = 0; i < 4; ++i) {
        int lin = tid + 256 * i;
        int r = lin >> 3, c4 = (lin & 7) * 4;
        uint2 v = make_uint2(0u, 0u);
        if (r0 + r < nrows) v = *(const uint2*)(A + (size_t)(r0 + r) * K + k0 + c4);
        *(uint2*)(&As[r * LD + c4]) = v;
      }
      // stage B tile: BN x 32 f16 (coalesced 16B per lane)
      #pragma unroll
      for (int i = 0; i < BN / 64; ++i) {
        int lin = tid + 256 * i;
        int n = lin >> 2, q = lin & 3;
        uint4 v = *(const uint4*)(B1t + 0, Bt + (size_t)(c0 + n) * K + k0 + q * 8);
        *(uint4*)(&Bs[n * LD + q * 8]) = v;
      }
      __syncthreads();
      f16x8 a0 = *(const f16x8*)(&As[(wr0 + m16) * LD + quad * 8]);
      f16x8 a1 = *(const f16x8*)(&As[(wr0 + 16 + m16) * LD + quad * 8]);
      #pragma unroll
      for (int bt = 0; bt < BN / 16; ++bt) {
        f16x8 b = *(const f16x8*)(&Bs[(bt * 16 + m16) * LD + quad * 8]);
        acc[0][bt] = __builtin_amdgcn_mfma_f32_16x16x32_f16(a0, b, acc[0][bt], 0, 0, 0);
        acc[1][bt] = __builtin_amdgcn_mfma_f32_16x16x32_f16(a1, b, acc[1][bt], 0, 0, 0);
      }
      __syncthreads();
    }
  }
  #pragma unroll
  for (int rt = 0; rt < 2; ++rt) {
    #pragma unroll
    for (int bt = 0; bt < BN / 16; ++bt) {
      #pragma unroll
      for (int j = 0; j < 4; ++j) {
        int row = r0 + wr0 + rt * 16 + quad * 4 + j;
        if (row >= nrows) continue;
        int colp = c0 + bt * 16 + m16;
        float v = acc[rt][bt][j];
        if (bias) v += bias[colp];
        if (epi == 1) v = tanhf(v);
        size_t o = (size_t)row * ldc + colp;
        if (cf16) ((f16*)C)[o] = (f16)v;
        else ((float*)C)[o] = v;
      }
    }
  }
}

extern "C" void kernel_launch(void* const* d_in, const int* in_sizes, int n_in,
                              void* d_out, int out_size, void* d_ws, size_t ws_size,
                              hipStream_t stream) {
  const float* x  = (const float*)d_in[0];
  const int*   Ai = (const int*)d_in[1];
  const float* Av = (const float*)d_in[2];
  const int*   Li = (const int*)d_in[3];
  const float* Lv = (const float*)d_in[4];
  const float* gcn_w0 = (const float*)d_in[5];
  const float* gcn_b0 = (const float*)d_in[6];
  const float* pai1_0 = (const float*)d_in[7];
  const float* pai2_0 = (const float*)d_in[8];
  const float* w1_w0  = (const float*)d_in[9];
  const float* w1_b0  = (const float*)d_in[10];
  const float* w2_w0  = (const float*)d_in[11];
  const float* w2_b0  = (const float*)d_in[12];
  const float* gcn_w1 = (const float*)d_in[13];
  const float* gcn_b1 = (const float*)d_in[14];
  const float* pai1_1 = (const float*)d_in[15];
  const float* pai2_1 = (const float*)d_in[16];
  const float* w1_w1  = (const float*)d_in[17];
  const float* w1_b1  = (const float*)d_in[18];
  const float* w2_w1  = (const float*)d_in[19];
  const float* w2_b1  = (const float*)d_in[20];
  float* out = (float*)d_out;

  const int N = N_NODES, E = N_EDGES;
  const size_t NH = (size_t)N * 256;   // f16 elements per 256-wide matrix
  const size_t Nd = (size_t)N * 64;

  // ---- workspace carve (f16 regions first, 16B aligned) ----
  f16* xh  = (f16*)d_ws;               // N*256
  f16* R1  = xh + NH;                  // N*256 (T0h -> Zbh/Zemb0h)
  f16* R2  = R1 + NH;                  // N*256 (Ztp0h -> T1h/Ztp1h/Z1bh)
  f16* wts = R2 + NH;                  // 274432 f16 weight pool
  f16* gcn_w0t = wts;                  // 256x256 -> [256][256]
  f16* pai1_0t = gcn_w0t + 65536;
  f16* pai2_0t = pai1_0t + 65536;
  f16* w1_w0t  = pai2_0t + 65536;      // [64][256]
  f16* w2_w0t  = w1_w0t + 16384;
  f16* gcn_w1t = w2_w0t + 16384;       // [64][256]
  f16* pai2_1t = gcn_w1t + 16384;      // [64][256]
  f16* pai1_1t = pai2_1t + 16384;      // [64][64]
  f16* w1_w1t  = pai1_1t + 4096;
  f16* w2_w1t  = w1_w1t + 4096;
  int* iws = (int*)(((uintptr_t)(w2_w1t + 4096) + 255) & ~(uintptr_t)255);
  int*   colA = iws;                   // E
  float* valA = (float*)(colA + E);    // E
  int*   colL = (int*)(valA + E);      // E
  float* valL = (float*)(colL + E);    // E
  int*   rpA  = (int*)(valL + E);      // N+1
  int*   rpL  = rpA + (N + 1);         // N+1
  int*   cnt  = rpL + (N + 1);         // 4*N
  int* cntA = cnt, *cntL = cnt + N, *curA = cnt + 2 * N, *curL = cnt + 3 * N;

  // sub-regions of R2 after Ztp0h dies
  f16* T1h   = R2;
  f16* Ztp1h = R2 + Nd;
  f16* Z1bh  = R2 + 2 * Nd;

  // ---- conversions + CSR build ----
  xconv_k<<<(int)((NH / 4 + 255) / 256), 256, 0, stream>>>(x, xh, (int)(NH / 4));
  wconv_k<<<(65536 + 255) / 256, 256, 0, stream>>>(gcn_w0, gcn_w0t, 256, 256);
  wconv_k<<<(65536 + 255) / 256, 256, 0, stream>>>(pai1_0, pai1_0t, 256, 256);
  wconv_k<<<(65536 + 255) / 256, 256, 0, stream>>>(pai2_0, pai2_0t, 256, 256);
  wconv_k<<<(16384 + 255) / 256, 256, 0, stream>>>(w1_w0, w1_w0t, 256, 64);
  wconv_k<<<(16384 + 255) / 256, 256, 0, stream>>>(w2_w0, w2_w0t, 256, 64);
  wconv_k<<<(16384 + 255) / 256, 256, 0, stream>>>(gcn_w1, gcn_w1t, 256, 64);
  wconv_k<<<(16384 + 255) / 256, 256, 0, stream>>>(pai2_1, pai2_1t, 256, 64);
  wconv_k<<<(4096 + 255) / 256, 256, 0, stream>>>(pai1_1, pai1_1t, 64, 64);
  wconv_k<<<(4096 + 255) / 256, 256, 0, stream>>>(w1_w1, w1_w1t, 64, 64);
  wconv_k<<<(4096 + 255) / 256, 256, 0, stream>>>(w2_w1, w2_w1t, 64, 64);

  hipMemsetAsync(cnt, 0, sizeof(int) * 4 * (size_t)N, stream);
  hist_k<<<(E + 255) / 256, 256, 0, stream>>>(Ai, Li, cntA, cntL, E);
  scan_k<<<2, 1024, 0, stream>>>(cntA, rpA, cntL, rpL, N);
  scatter_k<<<(E + 255) / 256, 256, 0, stream>>>(Ai, Av, rpA, curA, colA, valA,
                                                 Li, Lv, rpL, curL, colL, valL, E);

  const int MB = (N + 127) / 128;  // 782
  dim3 g256(MB, 2), g64(MB, 1);
  const int spmm_grid = (N + 3) / 4;

  // ---- layer 0 ----
  // T0h = xh @ gcn_w0                      (f16 out, R1)
  gemm_k<128><<<g256, 256, 0, stream>>>(xh, 256, nullptr, 0, gcn_w0t, nullptr, nullptr, R1, 1, 0, N, 256);
  // Ztp0h = relu(A @ T0h + gcn_b0)         (R2)
  spmm_k<4><<<spmm_grid, 256, 0, stream>>>(rpA, colA, valA, R1, nullptr, gcn_b0, R2, 0, N);
  // out0 = tanh(Ztp0h @ w1_w0 + w1_b0)     (fp32 out)
  gemm_k<64><<<g64, 256, 0, stream>>>(R2, 256, nullptr, 0, w1_w0t, nullptr, w1_b0, out, 0, 1, N, 64);
  // Zbh = Ztp0h @ pai1_0 + xh @ pai2_0     (R1)
  gemm_k<128><<<g256, 256, 0, stream>>>(R2, 256, xh, 256, pai1_0t, pai2_0t, nullptr, R1, 1, 0, N, 256);
  // Zemb0h = act(Zbh - L @ Ztp0h)          (R1, in place)
  spmm_k<4><<<spmm_grid, 256, 0, stream>>>(rpL, colL, valL, R2, R1, nullptr, R1, 1, N);
  // out2 = tanh(Zemb0h @ w2_w0 + w2_b0)
  gemm_k<64><<<g64, 256, 0, stream>>>(R1, 256, nullptr, 0, w2_w0t, nullptr, w2_b0, out + 2 * Nd, 0, 1, N, 64);

  // ---- layer 1 ----
  // T1h = Zemb0h @ gcn_w1
  gemm_k<64><<<g64, 256, 0, stream>>>(R1, 256, nullptr, 0, gcn_w1t, nullptr, nullptr, T1h, 1, 0, N, 64);
  // Ztp1h = relu(A @ T1h + gcn_b1)
  spmm_k<1><<<spmm_grid, 256, 0, stream>>>(rpA, colA, valA, T1h, nullptr, gcn_b1, Ztp1h, 0, N);
  // out1 = tanh(Ztp1h @ w1_w1 + w1_b1)
  gemm_k<64><<<g64, 256, 0, stream>>>(Ztp1h, 64, nullptr, 0, w1_w1t, nullptr, w1_b1, out + Nd, 0, 1, N, 64);
  // Z1bh = Ztp1h @ pai1_1 + xh @ pai2_1
  gemm_k<64><<<g64, 256, 0, stream>>>(Ztp1h, 64, xh, 256, pai1_1t, pai2_1t, nullptr, Z1bh, 1, 0, N, 64);
  // Zemb1h = act(Z1bh - L @ Ztp1h)         (in place)
  spmm_k<1><<<spmm_grid, 256, 0, stream>>>(rpL, colL, valL, Ztp1h, Z1bh, nullptr, Z1bh, 1, N);
  // out3 = tanh(Zemb1h @ w2_w1 + w2_b1)
  gemm_k<64><<<g64, 256, 0, stream>>>(Z1bh, 64, nullptr, 0, w2_w1t, nullptr, w2_b1, out + 3 * Nd, 0, 1, N, 64);
}

// Round 5
// 1273.949 us; speedup vs baseline: 2.0273x; 1.2480x over previous
//
#include <hip/hip_runtime.h>
#include <hip/hip_bf16.h>
#include <stdint.h>

static constexpr int N_NODES = 100000;
static constexpr int N_EDGES = 1600000;
static constexpr int PAD_ROWS = 100096;   // 782 * 128, removes GEMM A-tile bounds checks

typedef _Float16 f16;
using f16x8 = __attribute__((ext_vector_type(8))) _Float16;
using f16x4v = __attribute__((ext_vector_type(4))) _Float16;
using f32x4 = __attribute__((ext_vector_type(4))) float;

__device__ __forceinline__ void gld_lds16(const void* g, void* l) {
  __builtin_amdgcn_global_load_lds((const __attribute__((address_space(1))) void*)g,
                                   (__attribute__((address_space(3))) void*)l, 16, 0, 0);
}

// piecewise multi-term ReLU activation: 1.8*soft(0.1) - 0.8*soft(0.5)
__device__ __forceinline__ float custom_act(float x) {
  float s1 = fmaxf(x - 0.1f, 0.f) - fmaxf(-x - 0.1f, 0.f);
  float s2 = fmaxf(x - 0.5f, 0.f) - fmaxf(-x - 0.5f, 0.f);
  return 1.8f * s1 - 0.8f * s2;
}

// ---------------- conversions ----------------
__global__ __launch_bounds__(256) void xconv_k(const float* __restrict__ src, f16* __restrict__ dst, int n4) {
  int i = blockIdx.x * 256 + threadIdx.x;
  if (i < n4) {
    float4 v = ((const float4*)src)[i];
    f16x4v h = {(f16)v.x, (f16)v.y, (f16)v.z, (f16)v.w};
    ((f16x4v*)dst)[i] = h;
  }
}
// fp32 [K][N] -> f16 [N][K]
__global__ __launch_bounds__(256) void wconv_k(const float* __restrict__ src, f16* __restrict__ dst, int K, int N) {
  int i = blockIdx.x * 256 + threadIdx.x;
  if (i < K * N) { int k = i / N, n = i - k * N; dst[n * K + k] = (f16)src[i]; }
}

// ---------------- CSR build ----------------
__global__ __launch_bounds__(256) void hist_k(const int* __restrict__ Ar, const int* __restrict__ Lr,
                                              int* __restrict__ cntA, int* __restrict__ cntL, int E) {
  int e = blockIdx.x * 256 + threadIdx.x;
  if (e < E) {
    atomicAdd(&cntA[Ar[e]], 1);
    atomicAdd(&cntL[Lr[e]], 1);
  }
}

__global__ __launch_bounds__(1024) void scan_k(const int* __restrict__ cntA, int* __restrict__ rpA,
                                               const int* __restrict__ cntL, int* __restrict__ rpL, int n) {
  const int* cnt = blockIdx.x ? cntL : cntA;
  int* rp = blockIdx.x ? rpL : rpA;
  __shared__ int wsum[16];
  __shared__ int carry_s;
  int tid = threadIdx.x, lane = tid & 63, wv = tid >> 6;
  if (tid == 0) carry_s = 0;
  __syncthreads();
  for (int base = 0; base < n; base += 1024) {
    int i = base + tid;
    int v = (i < n) ? cnt[i] : 0;
    int s = v;
    #pragma unroll
    for (int off = 1; off < 64; off <<= 1) {
      int t = __shfl_up(s, off, 64);
      if (lane >= off) s += t;
    }
    if (lane == 63) wsum[wv] = s;
    __syncthreads();
    if (wv == 0 && lane < 16) {
      int w = wsum[lane];
      #pragma unroll
      for (int off = 1; off < 16; off <<= 1) {
        int t = __shfl_up(w, off, 64);
        if (lane >= off) w += t;
      }
      wsum[lane] = w;
    }
    __syncthreads();
    int carry = carry_s;
    int woff = wv ? wsum[wv - 1] : 0;
    if (i < n) rp[i] = carry + woff + s - v;
    __syncthreads();
    if (tid == 1023) carry_s = carry + woff + s;
    __syncthreads();
  }
  if (tid == 0) rp[n] = carry_s;
}

// fused (col, val_bits) records: one 8B store per edge per matrix
__global__ __launch_bounds__(256) void scatter_k(const int* __restrict__ Ai, const float* __restrict__ Av,
                                                 const int* __restrict__ rpA, int* __restrict__ curA,
                                                 int2* __restrict__ recA,
                                                 const int* __restrict__ Li, const float* __restrict__ Lv,
                                                 const int* __restrict__ rpL, int* __restrict__ curL,
                                                 int2* __restrict__ recL, int E) {
  int e = blockIdx.x * 256 + threadIdx.x;
  if (e >= E) return;
  {
    int r = Ai[e];
    int p = rpA[r] + atomicAdd(&curA[r], 1);
    recA[p] = make_int2(Ai[E + e], __float_as_int(Av[e]));
  }
  {
    int r = Li[e];
    int p = rpL[r] + atomicAdd(&curL[r], 1);
    recL[p] = make_int2(Li[E + e], __float_as_int(Lv[e]));
  }
}

// ---------------- gather SpMM over f16 features, fp32 accumulate ----------------
// mode 0: out = relu(acc + bias);  mode 1: out = custom_act(base - acc) (in-place ok)
template<int VEC>
__global__ __launch_bounds__(256) void spmm_k(const int* __restrict__ rp, const int2* __restrict__ rec,
                                              const f16* __restrict__ X,
                                              const f16* __restrict__ base, const float* __restrict__ bias,
                                              f16* __restrict__ out, int mode, int nrows) {
  int lane = threadIdx.x & 63;
  int row = blockIdx.x * 4 + (threadIdx.x >> 6);
  if (row >= nrows) return;
  const int M = VEC * 64;
  int p0 = rp[row], p1 = rp[row + 1];
  float acc[VEC] = {};
  int p = p0;
  for (; p + 1 < p1; p += 2) {
    int2 e0 = rec[p], e1 = rec[p + 1];
    float v0 = __int_as_float(e0.y), v1 = __int_as_float(e1.y);
    if (VEC == 4) {
      f16x4v x0 = *(const f16x4v*)(X + (size_t)e0.x * M + lane * 4);
      f16x4v x1 = *(const f16x4v*)(X + (size_t)e1.x * M + lane * 4);
      #pragma unroll
      for (int j = 0; j < 4; ++j) acc[j] += v0 * (float)x0[j] + v1 * (float)x1[j];
    } else {
      float x0 = (float)X[(size_t)e0.x * M + lane];
      float x1 = (float)X[(size_t)e1.x * M + lane];
      acc[0] += v0 * x0 + v1 * x1;
    }
  }
  if (p < p1) {
    int2 e0 = rec[p];
    float v0 = __int_as_float(e0.y);
    if (VEC == 4) {
      f16x4v x0 = *(const f16x4v*)(X + (size_t)e0.x * M + lane * 4);
      #pragma unroll
      for (int j = 0; j < 4; ++j) acc[j] += v0 * (float)x0[j];
    } else {
      acc[0] += v0 * (float)X[(size_t)e0.x * M + lane];
    }
  }
  size_t o = (size_t)row * M + (size_t)lane * VEC;
  if (VEC == 4) {
    f16x4v r;
    if (mode == 0) {
      #pragma unroll
      for (int j = 0; j < 4; ++j) r[j] = (f16)fmaxf(acc[j] + bias[lane * 4 + j], 0.f);
    } else {
      f16x4v bv = *(const f16x4v*)(base + o);
      #pragma unroll
      for (int j = 0; j < 4; ++j) r[j] = (f16)custom_act((float)bv[j] - acc[j]);
    }
    *(f16x4v*)(out + o) = r;
  } else {
    if (mode == 0) out[o] = (f16)fmaxf(acc[0] + bias[lane], 0.f);
    else out[o] = (f16)custom_act((float)base[o] - acc[0]);
  }
}

// ---------------- f16 MFMA GEMM with global_load_lds staging ----------------
// C = epi(A1@B1 [+ A2@B2] + bias). A row-major (PAD_ROWS rows allocated, no load
// bounds checks); Bt pre-transposed f16 [N][K]; tile 128 x BN, BK=32,
// 4 waves x 32 rows, mfma_f32_16x16x32_f16 (layouts as verified in round 4).
template<int BN>
__global__ __launch_bounds__(256) void gemm_k(const f16* __restrict__ A1, int K1,
                                              const f16* __restrict__ A2, int K2,
                                              const f16* __restrict__ B1t, const f16* __restrict__ B2t,
                                              const float* __restrict__ bias,
                                              void* __restrict__ C, int cf16, int epi,
                                              int nrows, int ldc) {
  __shared__ f16 As[128 * 32];
  __shared__ f16 Bs[BN * 32];
  int tid = threadIdx.x, lane = tid & 63, wv = tid >> 6;
  int m16 = lane & 15, quad = lane >> 4;
  int r0 = blockIdx.x * 128, c0 = blockIdx.y * BN;
  int wr0 = wv * 32;
  f32x4 acc[2][BN / 16] = {};
  // staging geometry: lane l stages row base+(l>>2), granule l&3 -> lds base + 16B*l
  int srow = lane >> 2, scol = (lane & 3) * 8;
  for (int src = 0; src < 2; ++src) {
    const f16* A = src ? A2 : A1;
    if (!A) continue;
    int K = src ? K2 : K1;
    const f16* Bt = src ? B2t : B1t;
    const f16* gA = A + (size_t)(r0 + wr0 + srow) * K + scol;
    const f16* gB = (BN == 128) ? Bt + (size_t)(c0 + wr0 + srow) * K + scol
                                : Bt + (size_t)(c0 + wv * 16 + srow) * K + scol;
    f16* lA = &As[wr0 * 32];
    f16* lB = (BN == 128) ? &Bs[wr0 * 32] : &Bs[wv * 16 * 32];
    for (int k0 = 0; k0 < K; k0 += 32) {
      gld_lds16(gA + k0, lA);
      gld_lds16(gA + k0 + (size_t)16 * K, lA + 512);
      gld_lds16(gB + k0, lB);
      if (BN == 128) gld_lds16(gB + k0 + (size_t)16 * K, lB + 512);
      __syncthreads();
      f16x8 a0 = *(const f16x8*)&As[(wr0 + m16) * 32 + quad * 8];
      f16x8 a1 = *(const f16x8*)&As[(wr0 + 16 + m16) * 32 + quad * 8];
      #pragma unroll
      for (int bt = 0; bt < BN / 16; ++bt) {
        f16x8 b = *(const f16x8*)&Bs[(bt * 16 + m16) * 32 + quad * 8];
        acc[0][bt] = __builtin_amdgcn_mfma_f32_16x16x32_f16(a0, b, acc[0][bt], 0, 0, 0);
        acc[1][bt] = __builtin_amdgcn_mfma_f32_16x16x32_f16(a1, b, acc[1][bt], 0, 0, 0);
      }
      __syncthreads();
    }
  }
  #pragma unroll
  for (int rt = 0; rt < 2; ++rt) {
    #pragma unroll
    for (int bt = 0; bt < BN / 16; ++bt) {
      #pragma unroll
      for (int j = 0; j < 4; ++j) {
        int row = r0 + wr0 + rt * 16 + quad * 4 + j;
        if (row >= nrows) continue;
        int colp = c0 + bt * 16 + m16;
        float v = acc[rt][bt][j];
        if (bias) v += bias[colp];
        if (epi == 1) v = tanhf(v);
        size_t o = (size_t)row * ldc + colp;
        if (cf16) ((f16*)C)[o] = (f16)v;
        else ((float*)C)[o] = v;
      }
    }
  }
}

extern "C" void kernel_launch(void* const* d_in, const int* in_sizes, int n_in,
                              void* d_out, int out_size, void* d_ws, size_t ws_size,
                              hipStream_t stream) {
  const float* x  = (const float*)d_in[0];
  const int*   Ai = (const int*)d_in[1];
  const float* Av = (const float*)d_in[2];
  const int*   Li = (const int*)d_in[3];
  const float* Lv = (const float*)d_in[4];
  const float* gcn_w0 = (const float*)d_in[5];
  const float* gcn_b0 = (const float*)d_in[6];
  const float* pai1_0 = (const float*)d_in[7];
  const float* pai2_0 = (const float*)d_in[8];
  const float* w1_w0  = (const float*)d_in[9];
  const float* w1_b0  = (const float*)d_in[10];
  const float* w2_w0  = (const float*)d_in[11];
  const float* w2_b0  = (const float*)d_in[12];
  const float* gcn_w1 = (const float*)d_in[13];
  const float* gcn_b1 = (const float*)d_in[14];
  const float* pai1_1 = (const float*)d_in[15];
  const float* pai2_1 = (const float*)d_in[16];
  const float* w1_w1  = (const float*)d_in[17];
  const float* w1_b1  = (const float*)d_in[18];
  const float* w2_w1  = (const float*)d_in[19];
  const float* w2_b1  = (const float*)d_in[20];
  float* out = (float*)d_out;

  const int N = N_NODES, E = N_EDGES;
  const size_t PH = (size_t)PAD_ROWS * 256;   // padded f16 elems per 256-wide matrix
  const size_t Pd = (size_t)PAD_ROWS * 64;
  const size_t Nd = (size_t)N * 64;

  // ---- workspace carve ----
  f16* xh  = (f16*)d_ws;               // PH
  f16* R1  = xh + PH;                  // PH
  f16* R2  = R1 + PH;                  // PH
  f16* wts = R2 + PH;                  // 274432 f16 weight pool
  f16* gcn_w0t = wts;
  f16* pai1_0t = gcn_w0t + 65536;
  f16* pai2_0t = pai1_0t + 65536;
  f16* w1_w0t  = pai2_0t + 65536;
  f16* w2_w0t  = w1_w0t + 16384;
  f16* gcn_w1t = w2_w0t + 16384;
  f16* pai2_1t = gcn_w1t + 16384;
  f16* pai1_1t = pai2_1t + 16384;
  f16* w1_w1t  = pai1_1t + 4096;
  f16* w2_w1t  = w1_w1t + 4096;
  int2* recA = (int2*)(((uintptr_t)(w2_w1t + 4096) + 255) & ~(uintptr_t)255);  // E
  int2* recL = recA + E;                                                        // E
  int*  rpA  = (int*)(recL + E);       // N+1
  int*  rpL  = rpA + (N + 1);          // N+1
  int*  cnt  = rpL + (N + 1);          // 4*N
  int* cntA = cnt, *cntL = cnt + N, *curA = cnt + 2 * N, *curL = cnt + 3 * N;

  // layer-1 sub-buffers inside R2 (ldc=64, padded rows)
  f16* T1h   = R2;
  f16* Ztp1h = R2 + Pd;
  f16* Z1bh  = R2 + 2 * Pd;

  // ---- conversions + CSR build ----
  xconv_k<<<(int)(((size_t)N * 64 + 255) / 256), 256, 0, stream>>>(x, xh, N * 64);
  wconv_k<<<(65536 + 255) / 256, 256, 0, stream>>>(gcn_w0, gcn_w0t, 256, 256);
  wconv_k<<<(65536 + 255) / 256, 256, 0, stream>>>(pai1_0, pai1_0t, 256, 256);
  wconv_k<<<(65536 + 255) / 256, 256, 0, stream>>>(pai2_0, pai2_0t, 256, 256);
  wconv_k<<<(16384 + 255) / 256, 256, 0, stream>>>(w1_w0, w1_w0t, 256, 64);
  wconv_k<<<(16384 + 255) / 256, 256, 0, stream>>>(w2_w0, w2_w0t, 256, 64);
  wconv_k<<<(16384 + 255) / 256, 256, 0, stream>>>(gcn_w1, gcn_w1t, 256, 64);
  wconv_k<<<(16384 + 255) / 256, 256, 0, stream>>>(pai2_1, pai2_1t, 256, 64);
  wconv_k<<<(4096 + 255) / 256, 256, 0, stream>>>(pai1_1, pai1_1t, 64, 64);
  wconv_k<<<(4096 + 255) / 256, 256, 0, stream>>>(w1_w1, w1_w1t, 64, 64);
  wconv_k<<<(4096 + 255) / 256, 256, 0, stream>>>(w2_w1, w2_w1t, 64, 64);

  hipMemsetAsync(cnt, 0, sizeof(int) * 4 * (size_t)N, stream);
  hist_k<<<(E + 255) / 256, 256, 0, stream>>>(Ai, Li, cntA, cntL, E);
  scan_k<<<2, 1024, 0, stream>>>(cntA, rpA, cntL, rpL, N);
  scatter_k<<<(E + 255) / 256, 256, 0, stream>>>(Ai, Av, rpA, curA, recA,
                                                 Li, Lv, rpL, curL, recL, E);

  const int MB = PAD_ROWS / 128;  // 782
  dim3 g256(MB, 2), g64(MB, 1);
  const int spmm_grid = (N + 3) / 4;

  // ---- layer 0 ----
  gemm_k<128><<<g256, 256, 0, stream>>>(xh, 256, nullptr, 0, gcn_w0t, nullptr, nullptr, R1, 1, 0, N, 256);
  spmm_k<4><<<spmm_grid, 256, 0, stream>>>(rpA, recA, R1, nullptr, gcn_b0, R2, 0, N);
  gemm_k<64><<<g64, 256, 0, stream>>>(R2, 256, nullptr, 0, w1_w0t, nullptr, w1_b0, out, 0, 1, N, 64);
  gemm_k<128><<<g256, 256, 0, stream>>>(R2, 256, xh, 256, pai1_0t, pai2_0t, nullptr, R1, 1, 0, N, 256);
  spmm_k<4><<<spmm_grid, 256, 0, stream>>>(rpL, recL, R2, R1, nullptr, R1, 1, N);
  gemm_k<64><<<g64, 256, 0, stream>>>(R1, 256, nullptr, 0, w2_w0t, nullptr, w2_b0, out + 2 * Nd, 0, 1, N, 64);

  // ---- layer 1 ----
  gemm_k<64><<<g64, 256, 0, stream>>>(R1, 256, nullptr, 0, gcn_w1t, nullptr, nullptr, T1h, 1, 0, N, 64);
  spmm_k<1><<<spmm_grid, 256, 0, stream>>>(rpA, recA, T1h, nullptr, gcn_b1, Ztp1h, 0, N);
  gemm_k<64><<<g64, 256, 0, stream>>>(Ztp1h, 64, nullptr, 0, w1_w1t, nullptr, w1_b1, out + Nd, 0, 1, N, 64);
  gemm_k<64><<<g64, 256, 0, stream>>>(Ztp1h, 64, xh, 256, pai1_1t, pai2_1t, nullptr, Z1bh, 1, 0, N, 64);
  spmm_k<1><<<spmm_grid, 256, 0, stream>>>(rpL, recL, Ztp1h, Z1bh, nullptr, Z1bh, 1, N);
  gemm_k<64><<<g64, 256, 0, stream>>>(Z1bh, 64, nullptr, 0, w2_w1t, nullptr, w2_b1, out + 3 * Nd, 0, 1, N, 64);
}